// Round 1
// baseline (874.791 us; speedup 1.0000x reference)
//
#include <hip/hip_runtime.h>
#include <cstdint>
#include <cstddef>

typedef _Float16 f16;
typedef _Float16 f16x8 __attribute__((ext_vector_type(8)));
typedef _Float16 f16x4 __attribute__((ext_vector_type(4)));
typedef float    f32x4 __attribute__((ext_vector_type(4)));

template <int V> struct IC { static constexpr int v = V; };

// ---------------------------------------------------------------------------
__global__ __launch_bounds__(256) void cvt_f32_f16(const float* __restrict__ in,
                                                   f16* __restrict__ out, int n) {
  int i = (blockIdx.x * 256 + threadIdx.x) * 4;
  if (i < n) {
    float4 v = *(const float4*)(in + i);
    f16x4 h; h[0] = (f16)v.x; h[1] = (f16)v.y; h[2] = (f16)v.z; h[3] = (f16)v.w;
    *(f16x4*)(out + i) = h;
  }
}

// ---------------------------------------------------------------------------
// in [R][ldi] (C-col slice) -> out [C][R]
__global__ __launch_bounds__(256) void transpose_f16(const f16* __restrict__ in,
                                                     int ldi,
                                                     f16* __restrict__ out,
                                                     int R, int C) {
  __shared__ f16 tile[64][65];
  const int r0 = blockIdx.y * 64, c0 = blockIdx.x * 64;
  const int t = threadIdx.x;
#pragma unroll
  for (int p = 0; p < 2; p++) {
    int s = t + p * 256;
    int r = s >> 3, q = s & 7;
    f16x8 v = *(const f16x8*)(in + (size_t)(r0 + r) * ldi + c0 + q * 8);
#pragma unroll
    for (int e = 0; e < 8; e++) tile[r][q * 8 + e] = v[e];
  }
  __syncthreads();
#pragma unroll
  for (int p = 0; p < 2; p++) {
    int s = t + p * 256;
    int r = s >> 3, q = s & 7;
    f16x8 v;
#pragma unroll
    for (int e = 0; e < 8; e++) v[e] = tile[q * 8 + e][r];
    *(f16x8*)(out + (size_t)(c0 + r) * R + r0 + q * 8) = v;
  }
}

// ---------------------------------------------------------------------------
// 256x256-tile BT GEMM, 8-phase counted-vmcnt schedule (T2+T3+T4+T5).
//   512 threads = 8 waves (2 M x 4 N); per-wave output 128x64 (interleaved:
//   rows mh*128+i*32+wr*16, cols wc*64+nh*32+j*16).
//   LDS: 2 dbuf x 2 halves x [128][64] f16 for A and B (128 KiB) + 2x256 f32
//   alpha (MODE 2). 16B slot p of row r holds k-chunk p^(r&7): linear DMA
//   dest, pre-swizzled source, conflict-free ds_read_b128 (verified pattern).
//   Per K-tile (BK=64): 4 phases {ds-read subtile | stage 1 half-tile ->
//   barrier -> lgkmcnt(0) -> setprio(1) 16 MFMA setprio(0) -> barrier};
//   stage order ph1:Ah1(t+1)[+alpha(t+1)] ph2:Ah0(t+2) ph3:Bh0(t+2)
//   ph4:Bh1(t+2)+vmcnt(6). vmcnt(6) leaves exactly the 3 half-tiles of t+2
//   in flight => tile t+1 fully landed before its first phase.
// MODE 0: outH = acc + bias[n]                                  (QKV merged)
// MODE 1: outH = exp(acc - tile64_rowmax); statsM/S per (row,64tile)   (S)
// MODE 2: A fragments scaled by alphaT[kt][row] (staged via LDS)     (ctx)
// MODE 3: outF = acc + bias + resid (f32); outH same (f16)           (fc0)
// MODE 4: outF = acc + bias (f32)                                    (fc1)
// ---------------------------------------------------------------------------
template <int MODE>
__global__ __launch_bounds__(512, 2) void gemm256(
    const f16* __restrict__ A, const f16* __restrict__ B,
    int M, int N, int K, int lda, int ldb,
    const float* __restrict__ bias,
    f16* __restrict__ outH, int ldo,
    float* __restrict__ statsM, float* __restrict__ statsS, int sld,
    const float* __restrict__ alphaT,
    const float* __restrict__ resid, int ldr,
    float* __restrict__ outF, int ldof) {
  __shared__ f16 lA[2][2][128 * 64];
  __shared__ f16 lB[2][2][128 * 64];
  __shared__ float lAl[2][256];

  const int t = threadIdx.x;
  const int wave = t >> 6, lane = t & 63;
  const int wr = wave >> 2, wc = wave & 3;
  const int quad = lane >> 4, l16 = lane & 15;
  const int rc = lane >> 3;
  const int kcs = (lane & 7) ^ rc;

  // XCD-aware swizzle: all grids here have nwg % 8 == 0.
  const int nwg = gridDim.x * gridDim.y;
  const int bid = blockIdx.y * gridDim.x + blockIdx.x;
  const int sb = (bid & 7) * (nwg >> 3) + (bid >> 3);
  const int bx = sb % gridDim.x, by = sb / gridDim.x;
  const int m0 = by * 256, n0 = bx * 256;
  const int nk = K >> 6;

  const f16* Abase = A + (size_t)m0 * lda;
  const f16* Bbase = B + (size_t)n0 * ldb;

  auto stageA = [&](int tau, int h) {
    if (tau >= nk) return;
    const f16* src = Abase + (size_t)(h * 128 + rc) * lda + tau * 64 + kcs * 8;
    f16* dstu = &lA[tau & 1][h][0];
#pragma unroll
    for (int j = 0; j < 2; j++) {
      const int sl = j * 8 + wave;
      __builtin_amdgcn_global_load_lds(
          (const __attribute__((address_space(1))) void*)(src + (size_t)sl * 8 * lda),
          (__attribute__((address_space(3))) void*)(dstu + sl * 512), 16, 0, 0);
    }
  };
  auto stageB = [&](int tau, int h) {
    if (tau >= nk) return;
    const f16* src = Bbase + (size_t)(h * 128 + rc) * ldb + tau * 64 + kcs * 8;
    f16* dstu = &lB[tau & 1][h][0];
#pragma unroll
    for (int j = 0; j < 2; j++) {
      const int sl = j * 8 + wave;
      __builtin_amdgcn_global_load_lds(
          (const __attribute__((address_space(1))) void*)(src + (size_t)sl * 8 * ldb),
          (__attribute__((address_space(3))) void*)(dstu + sl * 512), 16, 0, 0);
    }
  };
  auto stageAl = [&](int tau) {
    if constexpr (MODE == 2) {
      if (tau >= nk) return;
      __builtin_amdgcn_global_load_lds(
          (const __attribute__((address_space(1))) void*)(alphaT + (size_t)tau * M + m0 + lane * 4),
          (__attribute__((address_space(3))) void*)(&lAl[tau & 1][0]), 16, 0, 0);
    }
  };

  f32x4 acc[2][4][2][2];
#pragma unroll
  for (int mh = 0; mh < 2; mh++)
#pragma unroll
    for (int i = 0; i < 4; i++)
#pragma unroll
      for (int nh = 0; nh < 2; nh++)
#pragma unroll
        for (int j = 0; j < 2; j++)
#pragma unroll
          for (int e = 0; e < 4; e++) acc[mh][i][nh][j][e] = 0.0f;

  f16x8 af[4][2];
  f16x8 bf[2][2][2];  // [nh][j][ksub]

  auto readA = [&](auto BUFC, auto MHC) {
    constexpr int buf = decltype(BUFC)::v;
    constexpr int mh = decltype(MHC)::v;
#pragma unroll
    for (int i = 0; i < 4; i++) {
      const int r = i * 32 + wr * 16 + l16;
#pragma unroll
      for (int s = 0; s < 2; s++) {
        const int p = ((s * 4 + quad) ^ (l16 & 7)) * 8;
        af[i][s] = *(const f16x8*)(&lA[buf][mh][r * 64 + p]);
      }
      if constexpr (MODE == 2) {
        const f16 ah = (f16)lAl[buf][mh * 128 + r];
        af[i][0] = af[i][0] * ah;
        af[i][1] = af[i][1] * ah;
      }
    }
  };
  auto readB = [&](auto BUFC, auto NHC) {
    constexpr int buf = decltype(BUFC)::v;
    constexpr int nh = decltype(NHC)::v;
    const int hb = wc >> 1;
#pragma unroll
    for (int j = 0; j < 2; j++) {
      const int r = (wc & 1) * 64 + nh * 32 + j * 16 + l16;
#pragma unroll
      for (int s = 0; s < 2; s++) {
        const int p = ((s * 4 + quad) ^ (l16 & 7)) * 8;
        bf[nh][j][s] = *(const f16x8*)(&lB[buf][hb][r * 64 + p]);
      }
    }
  };
  auto mfmaQ = [&](auto MHC, auto NHC) {
    constexpr int mh = decltype(MHC)::v;
    constexpr int nh = decltype(NHC)::v;
    __builtin_amdgcn_s_setprio(1);
#pragma unroll
    for (int i = 0; i < 4; i++)
#pragma unroll
      for (int j = 0; j < 2; j++)
#pragma unroll
        for (int s = 0; s < 2; s++)
          acc[mh][i][nh][j] = __builtin_amdgcn_mfma_f32_16x16x32_f16(
              af[i][s], bf[nh][j][s], acc[mh][i][nh][j], 0, 0, 0);
    __builtin_amdgcn_s_setprio(0);
  };

  auto tile4 = [&](auto BUFC, int tt, bool dr) {
    // ph1: A-half0 + B-sub0 | stage Ah1(t+1) [+alpha(t+1)]
    readA(BUFC, IC<0>{});
    readB(BUFC, IC<0>{});
    stageA(tt + 1, 1);
    stageAl(tt + 1);
    __builtin_amdgcn_s_barrier();
    asm volatile("s_waitcnt lgkmcnt(0)" ::: "memory");
    mfmaQ(IC<0>{}, IC<0>{});
    __builtin_amdgcn_s_barrier();
    // ph2: B-sub1 | stage Ah0(t+2)
    readB(BUFC, IC<1>{});
    stageA(tt + 2, 0);
    __builtin_amdgcn_s_barrier();
    asm volatile("s_waitcnt lgkmcnt(0)" ::: "memory");
    mfmaQ(IC<0>{}, IC<1>{});
    __builtin_amdgcn_s_barrier();
    // ph3: A-half1 | stage Bh0(t+2)
    readA(BUFC, IC<1>{});
    stageB(tt + 2, 0);
    __builtin_amdgcn_s_barrier();
    asm volatile("s_waitcnt lgkmcnt(0)" ::: "memory");
    mfmaQ(IC<1>{}, IC<1>{});
    __builtin_amdgcn_s_barrier();
    // ph4: (B-sub0 frags still live) | stage Bh1(t+2) | counted vmcnt
    stageB(tt + 2, 1);
    __builtin_amdgcn_s_barrier();
    mfmaQ(IC<1>{}, IC<0>{});
    if (dr) { asm volatile("s_waitcnt vmcnt(0)" ::: "memory"); }
    else    { asm volatile("s_waitcnt vmcnt(6)" ::: "memory"); }
    __builtin_amdgcn_s_barrier();
  };

  // prologue: tile0 complete (+alpha0), tile1 {Ah0,Bh0,Bh1}
  stageA(0, 0); stageB(0, 0); stageB(0, 1); stageA(0, 1);
  stageAl(0);
  stageA(1, 0); stageB(1, 0); stageB(1, 1);
  asm volatile("s_waitcnt vmcnt(6)" ::: "memory");
  __builtin_amdgcn_s_barrier();

  for (int tt = 0; tt < nk; tt += 2) {
    const bool dr = (tt + 2 >= nk);
    tile4(IC<0>{}, tt, dr);
    tile4(IC<1>{}, tt + 1, dr);
  }

  // ---- epilogue ----
  const int colb = n0 + wc * 64 + l16;
  float bv[4];
  if constexpr (MODE == 0 || MODE == 3 || MODE == 4) {
#pragma unroll
    for (int c = 0; c < 4; c++) bv[c] = bias[colb + c * 16];
  }
#pragma unroll
  for (int mh = 0; mh < 2; mh++) {
#pragma unroll
    for (int i = 0; i < 4; i++) {
#pragma unroll
      for (int e = 0; e < 4; e++) {
        const int gr = m0 + mh * 128 + i * 32 + wr * 16 + quad * 4 + e;
        const float v0 = acc[mh][i][0][0][e];
        const float v1 = acc[mh][i][0][1][e];
        const float v2 = acc[mh][i][1][0][e];
        const float v3 = acc[mh][i][1][1][e];
        if constexpr (MODE == 1) {
          float mx = fmaxf(fmaxf(v0, v1), fmaxf(v2, v3));
          mx = fmaxf(mx, __shfl_xor(mx, 1));
          mx = fmaxf(mx, __shfl_xor(mx, 2));
          mx = fmaxf(mx, __shfl_xor(mx, 4));
          mx = fmaxf(mx, __shfl_xor(mx, 8));
          float e0 = __expf(v0 - mx);
          float e1 = __expf(v1 - mx);
          float e2 = __expf(v2 - mx);
          float e3 = __expf(v3 - mx);
          float sm = (e0 + e1) + (e2 + e3);
          sm += __shfl_xor(sm, 1);
          sm += __shfl_xor(sm, 2);
          sm += __shfl_xor(sm, 4);
          sm += __shfl_xor(sm, 8);
          if (l16 == 0) {
            statsM[(size_t)gr * sld + (bx * 4 + wc)] = mx;
            statsS[(size_t)gr * sld + (bx * 4 + wc)] = sm;
          }
          f16* rp = outH + (size_t)gr * ldo + colb;
          rp[0]  = (f16)e0;
          rp[16] = (f16)e1;
          rp[32] = (f16)e2;
          rp[48] = (f16)e3;
        } else if constexpr (MODE == 0) {
          f16* rp = outH + (size_t)gr * ldo + colb;
          rp[0]  = (f16)(v0 + bv[0]);
          rp[16] = (f16)(v1 + bv[1]);
          rp[32] = (f16)(v2 + bv[2]);
          rp[48] = (f16)(v3 + bv[3]);
        } else if constexpr (MODE == 2) {
          f16* rp = outH + (size_t)gr * ldo + colb;
          rp[0]  = (f16)v0;
          rp[16] = (f16)v1;
          rp[32] = (f16)v2;
          rp[48] = (f16)v3;
        } else if constexpr (MODE == 3) {
          float* rf = outF + (size_t)gr * ldof + colb;
          const float* rr = resid + (size_t)gr * ldr + colb;
          f16* rh = outH + (size_t)gr * ldo + colb;
          float o0 = v0 + bv[0] + rr[0];
          float o1 = v1 + bv[1] + rr[16];
          float o2 = v2 + bv[2] + rr[32];
          float o3 = v3 + bv[3] + rr[48];
          rf[0] = o0; rf[16] = o1; rf[32] = o2; rf[48] = o3;
          rh[0] = (f16)o0; rh[16] = (f16)o1; rh[32] = (f16)o2; rh[48] = (f16)o3;
        } else {  // MODE 4
          float* rf = outF + (size_t)gr * ldof + colb;
          rf[0]  = v0 + bv[0];
          rf[16] = v1 + bv[1];
          rf[32] = v2 + bv[2];
          rf[48] = v3 + bv[3];
        }
      }
    }
  }
}

// ---------------------------------------------------------------------------
// Per-row softmax factors from per-tile (max, sum):
//   m = max_t m_t;  l = sum_t exp(m_t - m) * s_t;  alphaT[t][row] = exp(m_t-m)/l
// ---------------------------------------------------------------------------
__global__ __launch_bounds__(256) void alpha_from_stats(
    const float* __restrict__ sM, const float* __restrict__ sS,
    float* __restrict__ aT, int rows) {
  __shared__ float alph[128][65];
  const int t = threadIdx.x;
  const int r = t >> 2, j = t & 3;
  const int row = blockIdx.x * 64 + r;
  const float* pm = sM + (size_t)row * 128 + j * 32;
  const float* ps = sS + (size_t)row * 128 + j * 32;
  float mv[32];
  float mx = -1e30f;
#pragma unroll
  for (int c = 0; c < 32; c++) { mv[c] = pm[c]; mx = fmaxf(mx, mv[c]); }
  mx = fmaxf(mx, __shfl_xor(mx, 1));
  mx = fmaxf(mx, __shfl_xor(mx, 2));
  float ev[32];
  float sum = 0.0f;
#pragma unroll
  for (int c = 0; c < 32; c++) {
    ev[c] = __expf(mv[c] - mx);
    sum += ev[c] * ps[c];
  }
  sum += __shfl_xor(sum, 1);
  sum += __shfl_xor(sum, 2);
  const float rl = 1.0f / sum;
#pragma unroll
  for (int c = 0; c < 32; c++) alph[j * 32 + c][r] = ev[c] * rl;
  __syncthreads();
  const int wid = t >> 6, rr = t & 63;
#pragma unroll
  for (int c = 0; c < 32; c++) {
    const int tg = c * 4 + wid;
    aT[(size_t)tg * rows + blockIdx.x * 64 + rr] = alph[tg][rr];
  }
}

// ---------------------------------------------------------------------------
extern "C" void kernel_launch(void* const* d_in, const int* in_sizes, int n_in,
                              void* d_out, int out_size, void* d_ws, size_t ws_size,
                              hipStream_t stream) {
  const float* O0   = (const float*)d_in[0];
  const float* Ww   = (const float*)d_in[1];
  const float* Wb   = (const float*)d_in[2];
  const float* Uw   = (const float*)d_in[3];
  const float* Ub   = (const float*)d_in[4];
  const float* Hw   = (const float*)d_in[5];
  const float* Hb   = (const float*)d_in[6];
  const float* fc0w = (const float*)d_in[7];
  const float* fc0b = (const float*)d_in[8];
  const float* fc1w = (const float*)d_in[9];
  const float* fc1b = (const float*)d_in[10];

  const int N = 8192, D = 2048, DH = 1024, DO = 1024;
  const int NQKV = 3 * DH;

  // workspace (~168 MB)
  char* w = (char*)d_ws;
  f16* Wwh   = (f16*)w; w += (size_t)DH * D * 2;   // W|U|H contiguous = merged B
  f16* Uwh   = (f16*)w; w += (size_t)DH * D * 2;
  f16* Hwh   = (f16*)w; w += (size_t)DH * D * 2;
  f16* fc0wh = (f16*)w; w += (size_t)D * DH * 2;
  f16* fc1wh = (f16*)w; w += (size_t)DO * D * 2;
  float* aT  = (float*)w; w += (size_t)128 * N * 4;          // alive thru ctx
  char* un = w; w += (size_t)N * DH * 2;                     // stats then ctxh
  float* statsM = (float*)un;
  float* statsS = statsM + (size_t)N * 128;
  f16* ctxh = (f16*)un;
  float* biasC = (float*)w; w += (size_t)NQKV * 4;
  w = (char*)(((uintptr_t)w + 255) & ~(uintptr_t)255);
  f16* Sb = (f16*)w;                    // 128 MiB: S(exp'd) -> dead -> O1h

  f16* oh   = (f16*)d_out;
  f16* qkv  = oh;
  f16* qh   = qkv;
  f16* kh   = qkv + DH;
  f16* vh   = qkv + 2 * DH;
  f16* O0h  = oh + (size_t)N * NQKV;
  f16* vT   = O0h + (size_t)N * D;
  f16* O1h  = Sb;

  // 1) fp32 -> fp16 conversions + bias concat
  {
    int n = DH * D;
    int grid = n / 1024;
    cvt_f32_f16<<<grid, 256, 0, stream>>>(Ww, Wwh, n);
    cvt_f32_f16<<<grid, 256, 0, stream>>>(Uw, Uwh, n);
    cvt_f32_f16<<<grid, 256, 0, stream>>>(Hw, Hwh, n);
    cvt_f32_f16<<<grid, 256, 0, stream>>>(fc0w, fc0wh, n);
    cvt_f32_f16<<<grid, 256, 0, stream>>>(fc1w, fc1wh, n);
    cvt_f32_f16<<<(N * D) / 1024, 256, 0, stream>>>(O0, O0h, N * D);
    hipMemcpyAsync(biasC,          Wb, DH * 4, hipMemcpyDeviceToDevice, stream);
    hipMemcpyAsync(biasC + DH,     Ub, DH * 4, hipMemcpyDeviceToDevice, stream);
    hipMemcpyAsync(biasC + 2 * DH, Hb, DH * 4, hipMemcpyDeviceToDevice, stream);
  }

  // 2) merged QKV: [N][3072] = O0h @ [Ww;Uw;Hw]^T + biasC
  gemm256<0><<<dim3(NQKV / 256, N / 256), 512, 0, stream>>>(
      O0h, Wwh, N, NQKV, D, D, D, biasC,
      qkv, NQKV, nullptr, nullptr, 0, nullptr, nullptr, 0, nullptr, 0);

  // 3) v -> vT
  transpose_f16<<<dim3(DH / 64, N / 64), 256, 0, stream>>>(vh, NQKV, vT, N, DH);

  // 4) S tiles: store exp(s - tile_max) + per-(row,64tile) (max, sum)
  gemm256<1><<<dim3(N / 256, N / 256), 512, 0, stream>>>(
      qh, kh, N, N, DH, NQKV, NQKV, nullptr, Sb, N,
      statsM, statsS, 128, nullptr, nullptr, 0, nullptr, 0);

  // 5) alpha factors
  alpha_from_stats<<<N / 64, 256, 0, stream>>>(statsM, statsS, aT, N);

  // 6) ctx = softmax(S) @ v, via alpha-scaled A fragments
  gemm256<2><<<dim3(DH / 256, N / 256), 512, 0, stream>>>(
      Sb, vT, N, DH, N, N, N, nullptr, ctxh, DH,
      nullptr, nullptr, 0, aT, nullptr, 0, nullptr, 0);

  // 7) O1 = O0 + ctx @ fc0w^T + fc0b -> fp32 d_out + fp16 O1h
  gemm256<3><<<dim3(D / 256, N / 256), 512, 0, stream>>>(
      ctxh, fc0wh, N, D, DH, DH, DH, fc0b, O1h, D,
      nullptr, nullptr, 0, nullptr, O0, D, (float*)d_out, D);

  // 8) O2 = O1 @ fc1w^T + fc1b
  gemm256<4><<<dim3(DO / 256, N / 256), 512, 0, stream>>>(
      O1h, fc1wh, N, DO, D, D, D, fc1b, nullptr, 0,
      nullptr, nullptr, 0, nullptr, nullptr, 0,
      (float*)d_out + (size_t)N * D, DO);
}

// Round 2
// 759.369 us; speedup vs baseline: 1.1520x; 1.1520x over previous
//
#include <hip/hip_runtime.h>
#include <cstdint>
#include <cstddef>

typedef _Float16 f16;
typedef _Float16 f16x8 __attribute__((ext_vector_type(8)));
typedef _Float16 f16x4 __attribute__((ext_vector_type(4)));
typedef float    f32x4 __attribute__((ext_vector_type(4)));

template <int V> struct IC { static constexpr int v = V; };

// ---------------------------------------------------------------------------
__global__ __launch_bounds__(256) void cvt_f32_f16(const float* __restrict__ in,
                                                   f16* __restrict__ out, int n) {
  int i = (blockIdx.x * 256 + threadIdx.x) * 4;
  if (i < n) {
    float4 v = *(const float4*)(in + i);
    f16x4 h; h[0] = (f16)v.x; h[1] = (f16)v.y; h[2] = (f16)v.z; h[3] = (f16)v.w;
    *(f16x4*)(out + i) = h;
  }
}

// ---------------------------------------------------------------------------
// in [R][ldi] (C-col slice) -> out [C][R]
__global__ __launch_bounds__(256) void transpose_f16(const f16* __restrict__ in,
                                                     int ldi,
                                                     f16* __restrict__ out,
                                                     int R, int C) {
  __shared__ f16 tile[64][65];
  const int r0 = blockIdx.y * 64, c0 = blockIdx.x * 64;
  const int t = threadIdx.x;
#pragma unroll
  for (int p = 0; p < 2; p++) {
    int s = t + p * 256;
    int r = s >> 3, q = s & 7;
    f16x8 v = *(const f16x8*)(in + (size_t)(r0 + r) * ldi + c0 + q * 8);
#pragma unroll
    for (int e = 0; e < 8; e++) tile[r][q * 8 + e] = v[e];
  }
  __syncthreads();
#pragma unroll
  for (int p = 0; p < 2; p++) {
    int s = t + p * 256;
    int r = s >> 3, q = s & 7;
    f16x8 v;
#pragma unroll
    for (int e = 0; e < 8; e++) v[e] = tile[q * 8 + e][r];
    *(f16x8*)(out + (size_t)(c0 + r) * R + r0 + q * 8) = v;
  }
}

// ---------------------------------------------------------------------------
// 256x256-tile BT GEMM, 8-phase counted-vmcnt schedule. (passed R1 refcheck)
// Used where grid >= 256 blocks: MODE 0 (QKV), MODE 1 (S), MODE 3 (fc0).
// ---------------------------------------------------------------------------
template <int MODE>
__global__ __launch_bounds__(512, 2) void gemm256(
    const f16* __restrict__ A, const f16* __restrict__ B,
    int M, int N, int K, int lda, int ldb,
    const float* __restrict__ bias,
    f16* __restrict__ outH, int ldo,
    float* __restrict__ statsM, float* __restrict__ statsS, int sld,
    const float* __restrict__ alphaT,
    const float* __restrict__ resid, int ldr,
    float* __restrict__ outF, int ldof) {
  __shared__ f16 lA[2][2][128 * 64];
  __shared__ f16 lB[2][2][128 * 64];
  __shared__ float lAl[2][256];

  const int t = threadIdx.x;
  const int wave = t >> 6, lane = t & 63;
  const int wr = wave >> 2, wc = wave & 3;
  const int quad = lane >> 4, l16 = lane & 15;
  const int rc = lane >> 3;
  const int kcs = (lane & 7) ^ rc;

  const int nwg = gridDim.x * gridDim.y;
  const int bid = blockIdx.y * gridDim.x + blockIdx.x;
  const int sb = (bid & 7) * (nwg >> 3) + (bid >> 3);
  const int bx = sb % gridDim.x, by = sb / gridDim.x;
  const int m0 = by * 256, n0 = bx * 256;
  const int nk = K >> 6;

  const f16* Abase = A + (size_t)m0 * lda;
  const f16* Bbase = B + (size_t)n0 * ldb;

  auto stageA = [&](int tau, int h) {
    if (tau >= nk) return;
    const f16* src = Abase + (size_t)(h * 128 + rc) * lda + tau * 64 + kcs * 8;
    f16* dstu = &lA[tau & 1][h][0];
#pragma unroll
    for (int j = 0; j < 2; j++) {
      const int sl = j * 8 + wave;
      __builtin_amdgcn_global_load_lds(
          (const __attribute__((address_space(1))) void*)(src + (size_t)sl * 8 * lda),
          (__attribute__((address_space(3))) void*)(dstu + sl * 512), 16, 0, 0);
    }
  };
  auto stageB = [&](int tau, int h) {
    if (tau >= nk) return;
    const f16* src = Bbase + (size_t)(h * 128 + rc) * ldb + tau * 64 + kcs * 8;
    f16* dstu = &lB[tau & 1][h][0];
#pragma unroll
    for (int j = 0; j < 2; j++) {
      const int sl = j * 8 + wave;
      __builtin_amdgcn_global_load_lds(
          (const __attribute__((address_space(1))) void*)(src + (size_t)sl * 8 * ldb),
          (__attribute__((address_space(3))) void*)(dstu + sl * 512), 16, 0, 0);
    }
  };
  auto stageAl = [&](int tau) {
    if constexpr (MODE == 2) {
      if (tau >= nk) return;
      __builtin_amdgcn_global_load_lds(
          (const __attribute__((address_space(1))) void*)(alphaT + (size_t)tau * M + m0 + lane * 4),
          (__attribute__((address_space(3))) void*)(&lAl[tau & 1][0]), 16, 0, 0);
    }
  };

  f32x4 acc[2][4][2][2];
#pragma unroll
  for (int mh = 0; mh < 2; mh++)
#pragma unroll
    for (int i = 0; i < 4; i++)
#pragma unroll
      for (int nh = 0; nh < 2; nh++)
#pragma unroll
        for (int j = 0; j < 2; j++)
#pragma unroll
          for (int e = 0; e < 4; e++) acc[mh][i][nh][j][e] = 0.0f;

  f16x8 af[4][2];
  f16x8 bf[2][2][2];  // [nh][j][ksub]

  auto readA = [&](auto BUFC, auto MHC) {
    constexpr int buf = decltype(BUFC)::v;
    constexpr int mh = decltype(MHC)::v;
#pragma unroll
    for (int i = 0; i < 4; i++) {
      const int r = i * 32 + wr * 16 + l16;
#pragma unroll
      for (int s = 0; s < 2; s++) {
        const int p = ((s * 4 + quad) ^ (l16 & 7)) * 8;
        af[i][s] = *(const f16x8*)(&lA[buf][mh][r * 64 + p]);
      }
      if constexpr (MODE == 2) {
        const f16 ah = (f16)lAl[buf][mh * 128 + r];
        af[i][0] = af[i][0] * ah;
        af[i][1] = af[i][1] * ah;
      }
    }
  };
  auto readB = [&](auto BUFC, auto NHC) {
    constexpr int buf = decltype(BUFC)::v;
    constexpr int nh = decltype(NHC)::v;
    const int hb = wc >> 1;
#pragma unroll
    for (int j = 0; j < 2; j++) {
      const int r = (wc & 1) * 64 + nh * 32 + j * 16 + l16;
#pragma unroll
      for (int s = 0; s < 2; s++) {
        const int p = ((s * 4 + quad) ^ (l16 & 7)) * 8;
        bf[nh][j][s] = *(const f16x8*)(&lB[buf][hb][r * 64 + p]);
      }
    }
  };
  auto mfmaQ = [&](auto MHC, auto NHC) {
    constexpr int mh = decltype(MHC)::v;
    constexpr int nh = decltype(NHC)::v;
    __builtin_amdgcn_s_setprio(1);
#pragma unroll
    for (int i = 0; i < 4; i++)
#pragma unroll
      for (int j = 0; j < 2; j++)
#pragma unroll
        for (int s = 0; s < 2; s++)
          acc[mh][i][nh][j] = __builtin_amdgcn_mfma_f32_16x16x32_f16(
              af[i][s], bf[nh][j][s], acc[mh][i][nh][j], 0, 0, 0);
    __builtin_amdgcn_s_setprio(0);
  };

  auto tile4 = [&](auto BUFC, int tt, bool dr) {
    readA(BUFC, IC<0>{});
    readB(BUFC, IC<0>{});
    stageA(tt + 1, 1);
    stageAl(tt + 1);
    __builtin_amdgcn_s_barrier();
    asm volatile("s_waitcnt lgkmcnt(0)" ::: "memory");
    mfmaQ(IC<0>{}, IC<0>{});
    __builtin_amdgcn_s_barrier();
    readB(BUFC, IC<1>{});
    stageA(tt + 2, 0);
    __builtin_amdgcn_s_barrier();
    asm volatile("s_waitcnt lgkmcnt(0)" ::: "memory");
    mfmaQ(IC<0>{}, IC<1>{});
    __builtin_amdgcn_s_barrier();
    readA(BUFC, IC<1>{});
    stageB(tt + 2, 0);
    __builtin_amdgcn_s_barrier();
    asm volatile("s_waitcnt lgkmcnt(0)" ::: "memory");
    mfmaQ(IC<1>{}, IC<1>{});
    __builtin_amdgcn_s_barrier();
    stageB(tt + 2, 1);
    __builtin_amdgcn_s_barrier();
    mfmaQ(IC<1>{}, IC<0>{});
    if (dr) { asm volatile("s_waitcnt vmcnt(0)" ::: "memory"); }
    else    { asm volatile("s_waitcnt vmcnt(6)" ::: "memory"); }
    __builtin_amdgcn_s_barrier();
  };

  stageA(0, 0); stageB(0, 0); stageB(0, 1); stageA(0, 1);
  stageAl(0);
  stageA(1, 0); stageB(1, 0); stageB(1, 1);
  asm volatile("s_waitcnt vmcnt(6)" ::: "memory");
  __builtin_amdgcn_s_barrier();

  for (int tt = 0; tt < nk; tt += 2) {
    const bool dr = (tt + 2 >= nk);
    tile4(IC<0>{}, tt, dr);
    tile4(IC<1>{}, tt + 1, dr);
  }

  // ---- epilogue ----
  const int colb = n0 + wc * 64 + l16;
  float bv[4];
  if constexpr (MODE == 0 || MODE == 3 || MODE == 4) {
#pragma unroll
    for (int c = 0; c < 4; c++) bv[c] = bias[colb + c * 16];
  }
#pragma unroll
  for (int mh = 0; mh < 2; mh++) {
#pragma unroll
    for (int i = 0; i < 4; i++) {
#pragma unroll
      for (int e = 0; e < 4; e++) {
        const int gr = m0 + mh * 128 + i * 32 + wr * 16 + quad * 4 + e;
        const float v0 = acc[mh][i][0][0][e];
        const float v1 = acc[mh][i][0][1][e];
        const float v2 = acc[mh][i][1][0][e];
        const float v3 = acc[mh][i][1][1][e];
        if constexpr (MODE == 1) {
          float mx = fmaxf(fmaxf(v0, v1), fmaxf(v2, v3));
          mx = fmaxf(mx, __shfl_xor(mx, 1));
          mx = fmaxf(mx, __shfl_xor(mx, 2));
          mx = fmaxf(mx, __shfl_xor(mx, 4));
          mx = fmaxf(mx, __shfl_xor(mx, 8));
          float e0 = __expf(v0 - mx);
          float e1 = __expf(v1 - mx);
          float e2 = __expf(v2 - mx);
          float e3 = __expf(v3 - mx);
          float sm = (e0 + e1) + (e2 + e3);
          sm += __shfl_xor(sm, 1);
          sm += __shfl_xor(sm, 2);
          sm += __shfl_xor(sm, 4);
          sm += __shfl_xor(sm, 8);
          if (l16 == 0) {
            statsM[(size_t)gr * sld + (bx * 4 + wc)] = mx;
            statsS[(size_t)gr * sld + (bx * 4 + wc)] = sm;
          }
          f16* rp = outH + (size_t)gr * ldo + colb;
          rp[0]  = (f16)e0;
          rp[16] = (f16)e1;
          rp[32] = (f16)e2;
          rp[48] = (f16)e3;
        } else if constexpr (MODE == 0) {
          f16* rp = outH + (size_t)gr * ldo + colb;
          rp[0]  = (f16)(v0 + bv[0]);
          rp[16] = (f16)(v1 + bv[1]);
          rp[32] = (f16)(v2 + bv[2]);
          rp[48] = (f16)(v3 + bv[3]);
        } else if constexpr (MODE == 2) {
          f16* rp = outH + (size_t)gr * ldo + colb;
          rp[0]  = (f16)v0;
          rp[16] = (f16)v1;
          rp[32] = (f16)v2;
          rp[48] = (f16)v3;
        } else if constexpr (MODE == 3) {
          float* rf = outF + (size_t)gr * ldof + colb;
          const float* rr = resid + (size_t)gr * ldr + colb;
          f16* rh = outH + (size_t)gr * ldo + colb;
          float o0 = v0 + bv[0] + rr[0];
          float o1 = v1 + bv[1] + rr[16];
          float o2 = v2 + bv[2] + rr[32];
          float o3 = v3 + bv[3] + rr[48];
          rf[0] = o0; rf[16] = o1; rf[32] = o2; rf[48] = o3;
          rh[0] = (f16)o0; rh[16] = (f16)o1; rh[32] = (f16)o2; rh[48] = (f16)o3;
        } else {
          float* rf = outF + (size_t)gr * ldof + colb;
          rf[0]  = v0 + bv[0];
          rf[16] = v1 + bv[1];
          rf[32] = v2 + bv[2];
          rf[48] = v3 + bv[3];
        }
      }
    }
  }
}

// ---------------------------------------------------------------------------
// 256x128-tile BT GEMM, same counted-vmcnt pipeline, for narrow-N GEMMs
// (N=1024 -> grid 8x32 = 256 blocks = exactly 1/CU; the 256x256 version
// starves half the machine there).
// 8 waves as 4M x 2N; per-wave output 64x64 (rows wr*64+i*16, cols
// wc*64+nh*32+j*16). Per K-tile: 2 phases x 16 MFMA.
//   ph1: read A-own-half (8 b128) + B both halves (8 b128) | stage Ah1(t+1)
//        [+alpha(t+1)] | barrier | lgkm0 | MFMA nh0 | barrier
//   ph2: (no ds reads) | stage Ah0(t+2), B(t+2) | barrier | MFMA nh1 |
//        vmcnt(4) | barrier
// Staging a region always happens >=1 barrier after its last ds_read
// completed (ph1 lgkm0 precedes ph1's trailing barrier). vmcnt(4) leaves the
// 2 stage-calls (4 loads) of t+2 in flight => t+1 (incl alpha, issued before
// them) resident at its first phase.
// MODE 2: A fragments scaled by alphaT[kt][row]; outH = acc         (ctx)
// MODE 4: outF = acc + bias (f32)                                   (fc1)
// ---------------------------------------------------------------------------
template <int MODE>
__global__ __launch_bounds__(512, 2) void gemmN128(
    const f16* __restrict__ A, const f16* __restrict__ B,
    int M, int N, int K, int lda, int ldb,
    const float* __restrict__ bias,
    f16* __restrict__ outH, int ldo,
    const float* __restrict__ alphaT,
    float* __restrict__ outF, int ldof) {
  __shared__ f16 lA[2][2][128 * 64];
  __shared__ f16 lB[2][128 * 64];
  __shared__ float lAl[2][256];

  const int t = threadIdx.x;
  const int wave = t >> 6, lane = t & 63;
  const int wr = wave >> 1, wc = wave & 1;   // 4M x 2N
  const int quad = lane >> 4, l16 = lane & 15;
  const int rc = lane >> 3;
  const int kcs = (lane & 7) ^ rc;

  const int nwg = gridDim.x * gridDim.y;
  const int bid = blockIdx.y * gridDim.x + blockIdx.x;
  const int sb = (bid & 7) * (nwg >> 3) + (bid >> 3);
  const int bx = sb % gridDim.x, by = sb / gridDim.x;
  const int m0 = by * 256, n0 = bx * 128;
  const int nk = K >> 6;

  const f16* Abase = A + (size_t)m0 * lda;
  const f16* Bbase = B + (size_t)n0 * ldb;

  auto stageA = [&](int tau, int h) {
    if (tau >= nk) return;
    const f16* src = Abase + (size_t)(h * 128 + rc) * lda + tau * 64 + kcs * 8;
    f16* dstu = &lA[tau & 1][h][0];
#pragma unroll
    for (int j = 0; j < 2; j++) {
      const int sl = j * 8 + wave;
      __builtin_amdgcn_global_load_lds(
          (const __attribute__((address_space(1))) void*)(src + (size_t)sl * 8 * lda),
          (__attribute__((address_space(3))) void*)(dstu + sl * 512), 16, 0, 0);
    }
  };
  auto stageB = [&](int tau) {
    if (tau >= nk) return;
    const f16* src = Bbase + (size_t)rc * ldb + tau * 64 + kcs * 8;
    f16* dstu = &lB[tau & 1][0];
#pragma unroll
    for (int j = 0; j < 2; j++) {
      const int sl = j * 8 + wave;
      __builtin_amdgcn_global_load_lds(
          (const __attribute__((address_space(1))) void*)(src + (size_t)sl * 8 * ldb),
          (__attribute__((address_space(3))) void*)(dstu + sl * 512), 16, 0, 0);
    }
  };
  auto stageAl = [&](int tau) {
    if constexpr (MODE == 2) {
      if (tau >= nk) return;
      __builtin_amdgcn_global_load_lds(
          (const __attribute__((address_space(1))) void*)(alphaT + (size_t)tau * M + m0 + lane * 4),
          (__attribute__((address_space(3))) void*)(&lAl[tau & 1][0]), 16, 0, 0);
    }
  };

  f32x4 acc[4][2][2];  // [i][nh][j]
#pragma unroll
  for (int i = 0; i < 4; i++)
#pragma unroll
    for (int nh = 0; nh < 2; nh++)
#pragma unroll
      for (int j = 0; j < 2; j++)
#pragma unroll
        for (int e = 0; e < 4; e++) acc[i][nh][j][e] = 0.0f;

  f16x8 af[4][2];
  f16x8 bf[2][2][2];  // [nh][j][ksub]
  const int ha = wr >> 1;

  auto readA = [&](auto BUFC) {
    constexpr int buf = decltype(BUFC)::v;
#pragma unroll
    for (int i = 0; i < 4; i++) {
      const int r = (wr & 1) * 64 + i * 16 + l16;
#pragma unroll
      for (int s = 0; s < 2; s++) {
        const int p = ((s * 4 + quad) ^ (l16 & 7)) * 8;
        af[i][s] = *(const f16x8*)(&lA[buf][ha][r * 64 + p]);
      }
      if constexpr (MODE == 2) {
        const f16 ah = (f16)lAl[buf][wr * 64 + i * 16 + l16];
        af[i][0] = af[i][0] * ah;
        af[i][1] = af[i][1] * ah;
      }
    }
  };
  auto readB = [&](auto BUFC, auto NHC) {
    constexpr int buf = decltype(BUFC)::v;
    constexpr int nh = decltype(NHC)::v;
#pragma unroll
    for (int j = 0; j < 2; j++) {
      const int r = wc * 64 + nh * 32 + j * 16 + l16;
#pragma unroll
      for (int s = 0; s < 2; s++) {
        const int p = ((s * 4 + quad) ^ (l16 & 7)) * 8;
        bf[nh][j][s] = *(const f16x8*)(&lB[buf][r * 64 + p]);
      }
    }
  };
  auto mfmaQ = [&](auto NHC) {
    constexpr int nh = decltype(NHC)::v;
    __builtin_amdgcn_s_setprio(1);
#pragma unroll
    for (int i = 0; i < 4; i++)
#pragma unroll
      for (int j = 0; j < 2; j++)
#pragma unroll
        for (int s = 0; s < 2; s++)
          acc[i][nh][j] = __builtin_amdgcn_mfma_f32_16x16x32_f16(
              af[i][s], bf[nh][j][s], acc[i][nh][j], 0, 0, 0);
    __builtin_amdgcn_s_setprio(0);
  };

  auto tile2 = [&](auto BUFC, int tt, bool dr) {
    readA(BUFC);
    readB(BUFC, IC<0>{});
    readB(BUFC, IC<1>{});
    stageA(tt + 1, 1);
    stageAl(tt + 1);
    __builtin_amdgcn_s_barrier();
    asm volatile("s_waitcnt lgkmcnt(0)" ::: "memory");
    mfmaQ(IC<0>{});
    __builtin_amdgcn_s_barrier();
    stageA(tt + 2, 0);
    stageB(tt + 2);
    __builtin_amdgcn_s_barrier();
    mfmaQ(IC<1>{});
    if (dr) { asm volatile("s_waitcnt vmcnt(0)" ::: "memory"); }
    else    { asm volatile("s_waitcnt vmcnt(4)" ::: "memory"); }
    __builtin_amdgcn_s_barrier();
  };

  // prologue: t0 complete (+alpha0); t1 {Ah0, B}
  stageA(0, 0); stageB(0); stageA(0, 1); stageAl(0);
  stageA(1, 0); stageB(1);
  asm volatile("s_waitcnt vmcnt(4)" ::: "memory");
  __builtin_amdgcn_s_barrier();

  for (int tt = 0; tt < nk; tt += 2) {
    const bool dr = (tt + 2 >= nk);
    tile2(IC<0>{}, tt, dr);
    tile2(IC<1>{}, tt + 1, dr);
  }

  // ---- epilogue ----
  float bv[2][2];
  if constexpr (MODE == 4) {
#pragma unroll
    for (int nh = 0; nh < 2; nh++)
#pragma unroll
      for (int j = 0; j < 2; j++)
        bv[nh][j] = bias[n0 + wc * 64 + nh * 32 + j * 16 + l16];
  }
#pragma unroll
  for (int i = 0; i < 4; i++) {
#pragma unroll
    for (int e = 0; e < 4; e++) {
      const int gr = m0 + wr * 64 + i * 16 + quad * 4 + e;
#pragma unroll
      for (int nh = 0; nh < 2; nh++) {
#pragma unroll
        for (int j = 0; j < 2; j++) {
          const int col = n0 + wc * 64 + nh * 32 + j * 16 + l16;
          const float v = acc[i][nh][j][e];
          if constexpr (MODE == 2) {
            outH[(size_t)gr * ldo + col] = (f16)v;
          } else {
            outF[(size_t)gr * ldof + col] = v + bv[nh][j];
          }
        }
      }
    }
  }
}

// ---------------------------------------------------------------------------
__global__ __launch_bounds__(256) void alpha_from_stats(
    const float* __restrict__ sM, const float* __restrict__ sS,
    float* __restrict__ aT, int rows) {
  __shared__ float alph[128][65];
  const int t = threadIdx.x;
  const int r = t >> 2, j = t & 3;
  const int row = blockIdx.x * 64 + r;
  const float* pm = sM + (size_t)row * 128 + j * 32;
  const float* ps = sS + (size_t)row * 128 + j * 32;
  float mv[32];
  float mx = -1e30f;
#pragma unroll
  for (int c = 0; c < 32; c++) { mv[c] = pm[c]; mx = fmaxf(mx, mv[c]); }
  mx = fmaxf(mx, __shfl_xor(mx, 1));
  mx = fmaxf(mx, __shfl_xor(mx, 2));
  float ev[32];
  float sum = 0.0f;
#pragma unroll
  for (int c = 0; c < 32; c++) {
    ev[c] = __expf(mv[c] - mx);
    sum += ev[c] * ps[c];
  }
  sum += __shfl_xor(sum, 1);
  sum += __shfl_xor(sum, 2);
  const float rl = 1.0f / sum;
#pragma unroll
  for (int c = 0; c < 32; c++) alph[j * 32 + c][r] = ev[c] * rl;
  __syncthreads();
  const int wid = t >> 6, rr = t & 63;
#pragma unroll
  for (int c = 0; c < 32; c++) {
    const int tg = c * 4 + wid;
    aT[(size_t)tg * rows + blockIdx.x * 64 + rr] = alph[tg][rr];
  }
}

// ---------------------------------------------------------------------------
extern "C" void kernel_launch(void* const* d_in, const int* in_sizes, int n_in,
                              void* d_out, int out_size, void* d_ws, size_t ws_size,
                              hipStream_t stream) {
  const float* O0   = (const float*)d_in[0];
  const float* Ww   = (const float*)d_in[1];
  const float* Wb   = (const float*)d_in[2];
  const float* Uw   = (const float*)d_in[3];
  const float* Ub   = (const float*)d_in[4];
  const float* Hw   = (const float*)d_in[5];
  const float* Hb   = (const float*)d_in[6];
  const float* fc0w = (const float*)d_in[7];
  const float* fc0b = (const float*)d_in[8];
  const float* fc1w = (const float*)d_in[9];
  const float* fc1b = (const float*)d_in[10];

  const int N = 8192, D = 2048, DH = 1024, DO = 1024;
  const int NQKV = 3 * DH;

  // workspace (~168 MB)
  char* w = (char*)d_ws;
  f16* Wwh   = (f16*)w; w += (size_t)DH * D * 2;   // W|U|H contiguous = merged B
  f16* Uwh   = (f16*)w; w += (size_t)DH * D * 2;
  f16* Hwh   = (f16*)w; w += (size_t)DH * D * 2;
  f16* fc0wh = (f16*)w; w += (size_t)D * DH * 2;
  f16* fc1wh = (f16*)w; w += (size_t)DO * D * 2;
  float* aT  = (float*)w; w += (size_t)128 * N * 4;          // alive thru ctx
  char* un = w; w += (size_t)N * DH * 2;                     // stats then ctxh
  float* statsM = (float*)un;
  float* statsS = statsM + (size_t)N * 128;
  f16* ctxh = (f16*)un;
  float* biasC = (float*)w; w += (size_t)NQKV * 4;
  w = (char*)(((uintptr_t)w + 255) & ~(uintptr_t)255);
  f16* Sb = (f16*)w;                    // 128 MiB: S(exp'd) -> dead -> O1h

  f16* oh   = (f16*)d_out;
  f16* qkv  = oh;
  f16* qh   = qkv;
  f16* kh   = qkv + DH;
  f16* vh   = qkv + 2 * DH;
  f16* O0h  = oh + (size_t)N * NQKV;
  f16* vT   = O0h + (size_t)N * D;
  f16* O1h  = Sb;

  // 1) fp32 -> fp16 conversions + bias concat
  {
    int n = DH * D;
    int grid = n / 1024;
    cvt_f32_f16<<<grid, 256, 0, stream>>>(Ww, Wwh, n);
    cvt_f32_f16<<<grid, 256, 0, stream>>>(Uw, Uwh, n);
    cvt_f32_f16<<<grid, 256, 0, stream>>>(Hw, Hwh, n);
    cvt_f32_f16<<<grid, 256, 0, stream>>>(fc0w, fc0wh, n);
    cvt_f32_f16<<<grid, 256, 0, stream>>>(fc1w, fc1wh, n);
    cvt_f32_f16<<<(N * D) / 1024, 256, 0, stream>>>(O0, O0h, N * D);
    hipMemcpyAsync(biasC,          Wb, DH * 4, hipMemcpyDeviceToDevice, stream);
    hipMemcpyAsync(biasC + DH,     Ub, DH * 4, hipMemcpyDeviceToDevice, stream);
    hipMemcpyAsync(biasC + 2 * DH, Hb, DH * 4, hipMemcpyDeviceToDevice, stream);
  }

  // 2) merged QKV: [N][3072] = O0h @ [Ww;Uw;Hw]^T + biasC  (384 blocks)
  gemm256<0><<<dim3(NQKV / 256, N / 256), 512, 0, stream>>>(
      O0h, Wwh, N, NQKV, D, D, D, biasC,
      qkv, NQKV, nullptr, nullptr, 0, nullptr, nullptr, 0, nullptr, 0);

  // 3) v -> vT
  transpose_f16<<<dim3(DH / 64, N / 64), 256, 0, stream>>>(vh, NQKV, vT, N, DH);

  // 4) S tiles: store exp(s - tile_max) + per-(row,64tile) (max, sum) (1024 blocks)
  gemm256<1><<<dim3(N / 256, N / 256), 512, 0, stream>>>(
      qh, kh, N, N, DH, NQKV, NQKV, nullptr, Sb, N,
      statsM, statsS, 128, nullptr, nullptr, 0, nullptr, 0);

  // 5) alpha factors
  alpha_from_stats<<<N / 64, 256, 0, stream>>>(statsM, statsS, aT, N);

  // 6) ctx = softmax(S) @ v, alpha-scaled A fragments (256 blocks, BN=128)
  gemmN128<2><<<dim3(DH / 128, N / 256), 512, 0, stream>>>(
      Sb, vT, N, DH, N, N, N, nullptr, ctxh, DH, aT, nullptr, 0);

  // 7) O1 = O0 + ctx @ fc0w^T + fc0b -> fp32 d_out + fp16 O1h (256 blocks)
  gemm256<3><<<dim3(D / 256, N / 256), 512, 0, stream>>>(
      ctxh, fc0wh, N, D, DH, DH, DH, fc0b, O1h, D,
      nullptr, nullptr, 0, nullptr, O0, D, (float*)d_out, D);

  // 8) O2 = O1 @ fc1w^T + fc1b (256 blocks, BN=128)
  gemmN128<4><<<dim3(DO / 128, N / 256), 512, 0, stream>>>(
      O1h, fc1wh, N, DO, D, D, D, fc1b, nullptr, 0, nullptr,
      (float*)d_out + (size_t)N * D, DO);
}